// Round 9
// baseline (107.324 us; speedup 1.0000x reference)
//
#include <hip/hip_runtime.h>
#include <hip/hip_bf16.h>
#include <stdint.h>

#define D 128
#define MCOLS 196      // 14*14
#define XPITCH 232     // xc pitch: 116 dwords == 20 mod 32 -> 2-way (minimum) on b128
#define BPITCH 136     // NS buffer pitch: 68 dwords == 4 mod 32 -> 2-way on b128
#define KOUT 8256      // 128*129/2

typedef short v8s __attribute__((ext_vector_type(8)));
typedef float v4f __attribute__((ext_vector_type(4)));

__device__ __forceinline__ uint32_t cvtpk(float a, float b) {
    __hip_bfloat162 h = __float22bfloat162_rn(make_float2(a, b));   // v_cvt_pk_bf16_f32
    uint32_t u;
    __builtin_memcpy(&u, &h, 4);
    return u;
}
__device__ __forceinline__ uint64_t pk64(float a, float b, float c, float d) {
    return (uint64_t)cvtpk(a, b) | ((uint64_t)cvtpk(c, d) << 32);
}
__device__ __forceinline__ float unlo(uint32_t u) { return __builtin_bit_cast(float, u << 16); }
__device__ __forceinline__ float unhi(uint32_t u) { return __builtin_bit_cast(float, u & 0xFFFF0000u); }

// Barrier WITHOUT vmcnt drain: keeps prefetch global_loads in flight across
// LDS-ordering barriers. lgkmcnt(0) orders all LDS ops; sched_barrier(0)
// prevents post-barrier ds ops hoisting above s_barrier.
__device__ __forceinline__ void barrier_nd() {
    asm volatile("s_waitcnt lgkmcnt(0)" ::: "memory");
    __builtin_amdgcn_s_barrier();
    __builtin_amdgcn_sched_barrier(0);
}

// Persistent: grid=256 (1 block/CU), 4 batches/block, batch k+1's input
// register-prefetched during batch k's NS chain (no-drain barriers keep loads
// in flight). 1024 threads = 16 waves (4/SIMD for latency hiding), 4x4 wave
// grid, 32x32 per wave (2x2 16x16 tiles, acc[2][2]); live regs ~80 << 128
// budget -> no spills. All NS matrices symmetric -> one row-major LDS copy
// serves both MFMA operands. M = c*I + R split; linear terms c*R over the
// wave's own region reloaded from LDS (transposed-contiguous b64), with the
// loads HOISTED before each stage's frag reads to hide latency.
__global__ __launch_bounds__(1024) void mpncov_kernel(const float* __restrict__ x,
                                                      float* __restrict__ out) {
    __shared__ __align__(16) uint16_t lds[4 * D * BPITCH];   // 139264 B
    __shared__ float redbuf[16];

    uint16_t* const B0 = lds;
    uint16_t* const B1 = lds + 1 * D * BPITCH;
    uint16_t* const B2 = lds + 2 * D * BPITCH;
    uint16_t* const B3 = lds + 3 * D * BPITCH;
    // xc (128 x 232 bf16 = 59392 B) overlays B1+B2 (69632 B). Rotation:
    // covM=B0, Y1=B1, ZY1=B2, Y2=B3, Z2=B1, T2=B0 -> B2 dead after MM4,
    // B1 dead after MM5 -> pack(k+1) runs during/after MM6.
    uint16_t (*const xc)[XPITCH] = reinterpret_cast<uint16_t(*)[XPITCH]>(B1);

    const int tid = threadIdx.x;
    const int lane = tid & 63;
    const int w = tid >> 6, wr = w >> 2, wc = w & 3;   // 4x4 wave grid
    const int lr = lane & 15, lk = lane >> 4;
    const int prow = tid >> 3, pq = tid & 7;           // prefetch: 8 threads/row

    // ---- cross-batch prefetch state: 49 float4 per row, 6(+1 tail) per thread ----
    float4 pf[6]; float4 pfT;

    auto issue_pf = [&](int bbn) {
        const float4* p4 = reinterpret_cast<const float4*>(x + (size_t)bbn * (D * MCOLS)) + 49 * prow;
#pragma unroll
        for (int i = 0; i < 6; ++i) pf[i] = p4[pq + 8 * i];
        if (pq == 0) pfT = p4[48];
    };
    // mean via 8-lane shfl, center exactly in f32, pack bf16, write xc + zero K-pad
    auto pack_pf = [&]() {
        float s = 0.f;
#pragma unroll
        for (int i = 0; i < 6; ++i) s += (pf[i].x + pf[i].y) + (pf[i].z + pf[i].w);
        if (pq == 0) s += (pfT.x + pfT.y) + (pfT.z + pfT.w);
        s += __shfl_xor(s, 1); s += __shfl_xor(s, 2); s += __shfl_xor(s, 4);
        const float m = s * (1.0f / MCOLS);
#pragma unroll
        for (int i = 0; i < 6; ++i)
            *reinterpret_cast<uint64_t*>(&xc[prow][4 * (pq + 8 * i)]) =
                pk64(pf[i].x - m, pf[i].y - m, pf[i].z - m, pf[i].w - m);
        if (pq == 0)
            *reinterpret_cast<uint64_t*>(&xc[prow][192]) =
                pk64(pfT.x - m, pfT.y - m, pfT.z - m, pfT.w - m);
        // zero K-pad cols 196..231 (inside B1/B2 -> must re-zero every round)
        for (int idx = tid; idx < D * 9; idx += 1024) {
            const int row = idx / 9, p = idx - 9 * row;
            *reinterpret_cast<uint64_t*>(&xc[row][MCOLS + 4 * p]) = 0ull;
        }
    };

    v4f acc[2][2];
    auto zacc = [&]() {
#pragma unroll
        for (int i = 0; i < 2; ++i)
#pragma unroll
            for (int j = 0; j < 2; ++j) acc[i][j] = v4f{0.f, 0.f, 0.f, 0.f};
    };
    auto matmul = [&](const uint16_t* P, const uint16_t* Q) {
        zacc();
#pragma unroll
        for (int kk = 0; kk < 4; ++kk) {
            const int k0 = kk * 32 + lk * 8;
            v8s af[2], bf[2];
#pragma unroll
            for (int i = 0; i < 2; ++i)
                af[i] = *reinterpret_cast<const v8s*>(&P[(32 * wr + 16 * i + lr) * BPITCH + k0]);
#pragma unroll
            for (int j = 0; j < 2; ++j)
                bf[j] = *reinterpret_cast<const v8s*>(&Q[(32 * wc + 16 * j + lr) * BPITCH + k0]);
#pragma unroll
            for (int i = 0; i < 2; ++i)
#pragma unroll
                for (int j = 0; j < 2; ++j)
                    acc[i][j] = __builtin_amdgcn_mfma_f32_16x16x32_bf16(af[i], bf[j], acc[i][j], 0, 0, 0);
        }
    };
    auto store_tile = [&](uint16_t* dst, int i, int j, const v4f& v) {   // transposed b64
        const int r0 = 32 * wr + 16 * i + 4 * lk;
        const int c  = 32 * wc + 16 * j + lr;
        *reinterpret_cast<uint64_t*>(&dst[c * BPITCH + r0]) = pk64(v[0], v[1], v[2], v[3]);
    };
    auto own_addr = [&](const uint16_t* src, int i, int j) -> const uint64_t* {
        const int r0 = 32 * wr + 16 * i + 4 * lk;
        const int c  = 32 * wc + 16 * j + lr;
        return reinterpret_cast<const uint64_t*>(&src[c * BPITCH + r0]);
    };
    auto unq = [&](uint64_t g) -> v4f {
        return v4f{unlo((uint32_t)g), unhi((uint32_t)g),
                   unlo((uint32_t)(g >> 32)), unhi((uint32_t)(g >> 32))};
    };

    // Generic NS stage: dst = sAcc*(P@Q) + sO1*own1 [+ sO2*own2], own loads hoisted.
    auto stage = [&](const uint16_t* P, const uint16_t* Q, uint16_t* dst,
                     const uint16_t* own1, float sAcc, float sO1,
                     const uint16_t* own2, float sO2) {
        uint64_t g1[2][2], g2[2][2];
#pragma unroll
        for (int i = 0; i < 2; ++i)
#pragma unroll
            for (int j = 0; j < 2; ++j) {
                g1[i][j] = *own_addr(own1, i, j);
                if (own2) g2[i][j] = *own_addr(own2, i, j);
            }
        matmul(P, Q);
#pragma unroll
        for (int i = 0; i < 2; ++i)
#pragma unroll
            for (int j = 0; j < 2; ++j) {
                const v4f o1 = unq(g1[i][j]);
                v4f v;
#pragma unroll
                for (int q = 0; q < 4; ++q) v[q] = sAcc * acc[i][j][q] + sO1 * o1[q];
                if (own2) {
                    const v4f o2 = unq(g2[i][j]);
#pragma unroll
                    for (int q = 0; q < 4; ++q) v[q] += sO2 * o2[q];
                }
                store_tile(dst, i, j, v);
            }
    };

    // ---- prologue: stage batch (4*blockIdx.x) ----
    issue_pf(4 * blockIdx.x);
    pack_pf();

    for (int it = 0; it < 4; ++it) {
        const int bb = 4 * blockIdx.x + it;
        barrier_nd();                               // xc(bb) ready

        if (it < 3) {                               // issue next batch's loads NOW;
            issue_pf(bb + 1);                       // they stay in flight across all
            __builtin_amdgcn_sched_barrier(0);      // no-drain barriers below
        }

        // ---- cov: covM = xc @ xc^T (centered, K padded to 224) ----
        zacc();
#pragma unroll
        for (int kk = 0; kk < 7; ++kk) {
            const int k0 = kk * 32 + lk * 8;
            v8s af[2], bf[2];
#pragma unroll
            for (int i = 0; i < 2; ++i)
                af[i] = *reinterpret_cast<const v8s*>(&xc[32 * wr + 16 * i + lr][k0]);
#pragma unroll
            for (int j = 0; j < 2; ++j)
                bf[j] = *reinterpret_cast<const v8s*>(&xc[32 * wc + 16 * j + lr][k0]);
#pragma unroll
            for (int i = 0; i < 2; ++i)
#pragma unroll
                for (int j = 0; j < 2; ++j)
                    acc[i][j] = __builtin_amdgcn_mfma_f32_16x16x32_bf16(af[i], bf[j], acc[i][j], 0, 0, 0);
        }

        // trace (C/D layout: col=lane&15, row=(lane>>4)*4+q)
        float tval = 0.f;
        if (wr == wc && (lr >> 2) == lk) {
            const int qq = lr & 3;
            tval = acc[0][0][qq] + acc[1][1][qq];
        }
#pragma unroll
        for (int off = 32; off; off >>= 1) tval += __shfl_down(tval, off);
        if (lane == 0) redbuf[w] = tval;

        // store covM (unnormalized; 1/tr folded into combine scalars below)
#pragma unroll
        for (int i = 0; i < 2; ++i)
#pragma unroll
            for (int j = 0; j < 2; ++j) store_tile(B0, i, j, acc[i][j]);
        barrier_nd();                               // covM + redbuf visible; xc dead

        float tr = 0.f;
#pragma unroll
        for (int t = 0; t < 16; ++t) tr += redbuf[t];
        const float inv = 1.0f / tr;
        const float outscale = sqrtf(tr * (1.0f / MCOLS));

        // MM1: RY1 = -0.5*inv^2*(C@C) + 1.5*inv*C        -> B1
        stage(B0, B0, B1, B0, -0.5f * inv * inv, 1.5f * inv, nullptr, 0.f);
        barrier_nd();
        // MM2: RZY1 = 0.25*inv*(C@RY1) - 0.75*RY1        -> B2
        stage(B0, B1, B2, B1, 0.25f * inv, -0.75f, nullptr, 0.f);
        barrier_nd();
        // MM3: RY2 = RY1@RZY1 + 1.5*RY1                  -> B3
        stage(B1, B2, B3, B1, 1.f, 1.5f, nullptr, 0.f);
        barrier_nd();
        // MM4: RZ2 = -0.5*inv*(RZY1@C) - 0.75*inv*C + 1.5*RZY1  -> B1
        stage(B2, B0, B1, B0, -0.5f * inv, -0.75f * inv, B2, 1.5f);
        barrier_nd();
        // MM5: RT2 = RZ2@RY2 + 2.25*RY2                  -> B0
        stage(B1, B3, B0, B3, 1.f, 2.25f, nullptr, 0.f);
        barrier_nd();                              // T2 ready; B1,B2 (=xc region) dead

        // MM6: O = (1.5*RY2 - 0.5*(RY2@RT2)) * outscale ; upper-tri only
        if (wr <= wc) {
            uint64_t g[2][2];
#pragma unroll
            for (int i = 0; i < 2; ++i)
#pragma unroll
                for (int j = 0; j < 2; ++j) g[i][j] = *own_addr(B3, i, j);
            zacc();
#pragma unroll
            for (int kk = 0; kk < 4; ++kk) {
                const int k0 = kk * 32 + lk * 8;
                v8s af[2], bf[2];
#pragma unroll
                for (int i = 0; i < 2; ++i)
                    af[i] = *reinterpret_cast<const v8s*>(&B3[(32 * wr + 16 * i + lr) * BPITCH + k0]);
#pragma unroll
                for (int j = 0; j < 2; ++j)
                    bf[j] = *reinterpret_cast<const v8s*>(&B0[(32 * wc + 16 * j + lr) * BPITCH + k0]);
#pragma unroll
                for (int i = 0; i < 2; ++i)
#pragma unroll
                    for (int j = 0; j < 2; ++j)
                        if (2 * wr + i <= 2 * wc + j)
                            acc[i][j] = __builtin_amdgcn_mfma_f32_16x16x32_bf16(af[i], bf[j], acc[i][j], 0, 0, 0);
            }
            float* ob = out + (size_t)bb * KOUT;
#pragma unroll
            for (int i = 0; i < 2; ++i) {
                const int r0 = 32 * wr + 16 * i + 4 * lk;
#pragma unroll
                for (int j = 0; j < 2; ++j) {
                    const int rb = 2 * wr + i, cb = 2 * wc + j;
                    if (rb > cb) continue;
                    const int c = 32 * wc + 16 * j + lr;
                    const v4f o = unq(g[i][j]);
                    float vv[4];
#pragma unroll
                    for (int q = 0; q < 4; ++q)
                        vv[q] = (1.5f * o[q] - 0.5f * acc[i][j][q]) * outscale;
                    if (rb < cb) {
#pragma unroll
                        for (int q = 0; q < 4; ++q) {
                            const int r = r0 + q;
                            ob[r * D - (r * (r + 1)) / 2 + c] = vv[q];
                        }
                    } else {
#pragma unroll
                        for (int q = 0; q < 4; ++q) {
                            const int r = r0 + q;
                            if (r <= c) ob[r * D - (r * (r + 1)) / 2 + c] = vv[q];
                        }
                    }
                }
            }
        }
        if (it < 3) pack_pf();                     // xc(bb+1) into B1/B2, overlaps MM6
    }
}

extern "C" void kernel_launch(void* const* d_in, const int* in_sizes, int n_in,
                              void* d_out, int out_size, void* d_ws, size_t ws_size,
                              hipStream_t stream) {
    const float* x = (const float*)d_in[0];
    float* out = (float*)d_out;
    mpncov_kernel<<<dim3(256), dim3(1024), 0, stream>>>(x, out);
}